// Round 1
// 888.206 us; speedup vs baseline: 1.0460x; 1.0460x over previous
//
#include <hip/hip_runtime.h>
#include <cstdint>
#include <cstddef>

typedef _Float16 f16x8 __attribute__((ext_vector_type(8)));
typedef _Float16 f16x4 __attribute__((ext_vector_type(4)));
typedef _Float16 f16x2 __attribute__((ext_vector_type(2)));
typedef float    f32x4 __attribute__((ext_vector_type(4)));

__device__ __forceinline__ void async16(const void* g, void* l) {
  __builtin_amdgcn_global_load_lds(
      (const __attribute__((address_space(1))) void*)g,
      (__attribute__((address_space(3))) void*)l, 16, 0, 0);
}

// ---------------- fp32 -> fp16 convert ----------------
__global__ void cvt_kernel(const float* __restrict__ in, _Float16* __restrict__ out, int n4) {
  int i = blockIdx.x * blockDim.x + threadIdx.x;
  int stride = gridDim.x * blockDim.x;
  for (; i < n4; i += stride) {
    float4 f = ((const float4*)in)[i];
    f16x4 o;
    o[0] = (_Float16)f.x; o[1] = (_Float16)f.y;
    o[2] = (_Float16)f.z; o[3] = (_Float16)f.w;
    ((f16x4*)out)[i] = o;
  }
}

// ---------------- RoPE, interleaved pairs, in place ----------------
__global__ void rope_kernel(_Float16* __restrict__ X, const int* __restrict__ sp,
                            int ppShift, int sMask, int nPairs) {
  int i = blockIdx.x * blockDim.x + threadIdx.x;
  int stride = gridDim.x * blockDim.x;
  int start = *sp;
  for (int p = i; p < nPairs; p += stride) {
    int row = p >> ppShift;
    int pc  = p & ((1 << ppShift) - 1);
    int fi  = pc & 63;                 // pair index within head (d/2 = 64)
    int s   = row & sMask;             // row = b*S + s
    float ang = (float)(start + s) * exp2f(-0.20762050593046014f * (float)fi);
    float sn, cs;
    __sincosf(ang, &sn, &cs);
    uint32_t u = ((uint32_t*)X)[p];
    f16x2 v = __builtin_bit_cast(f16x2, u);
    float x1 = (float)v[0], x2 = (float)v[1];
    v[0] = (_Float16)(x1 * cs - x2 * sn);
    v[1] = (_Float16)(x1 * sn + x2 * cs);
    ((uint32_t*)X)[p] = __builtin_bit_cast(uint32_t, v);
  }
}

// ---------------- NT GEMM: C = A(M,K) * B(N,K)^T ----------------
// OUT_MODE 0: f16 C row-major (ld=N)
// OUT_MODE 2: f32 C row-major (ld=N)
// OUT_MODE 3: split KV: cols [0,N/2) -> f16 Cp (ld=N/2); cols [N/2,N) -> f16 Cp2 transposed (ld=M)
template<int OUT_MODE>
__global__ __launch_bounds__(256, 3)
void gemm_nt(const _Float16* __restrict__ A, const _Float16* __restrict__ B,
             void* __restrict__ Cp, void* __restrict__ Cp2,
             int M, int N, int K) {
  __shared__ __align__(16) _Float16 As[128 * 64];
  __shared__ __align__(16) _Float16 Bs[128 * 64];
  const int tid  = threadIdx.x;
  const int wave = tid >> 6, lane = tid & 63;
  const int l15  = lane & 15, quad = lane >> 4;
  const int m0 = blockIdx.y * 128, n0 = blockIdx.x * 128;
  const int wm = (wave >> 1) * 64, wn = (wave & 1) * 64;
  f32x4 acc[4][4] = {};
  const int cbase = wave * 256;

  for (int kb = 0; kb < K; kb += 64) {
    // stage A,B tiles (128x64 f16 each) via global_load_lds, XOR chunk swizzle
    #pragma unroll
    for (int i = 0; i < 4; ++i) {
      int base = cbase + i * 64;
      int idx  = base + lane;          // chunk 0..1023
      int row  = idx >> 3, pos = idx & 7;
      int c    = pos ^ (row & 7);
      async16(A + (size_t)(m0 + row) * K + kb + c * 8, (char*)As + base * 16);
      async16(B + (size_t)(n0 + row) * K + kb + c * 8, (char*)Bs + base * 16);
    }
    __syncthreads();
    #pragma unroll
    for (int ks = 0; ks < 2; ++ks) {
      f16x8 af[4], bfv[4];
      #pragma unroll
      for (int t = 0; t < 4; ++t) {
        int ra = wm + t * 16 + l15;
        int pa = (ks * 4 + quad) ^ (ra & 7);
        af[t] = *(const f16x8*)((const char*)As + ra * 128 + pa * 16);
        int rb = wn + t * 16 + l15;
        int pb = (ks * 4 + quad) ^ (rb & 7);
        bfv[t] = *(const f16x8*)((const char*)Bs + rb * 128 + pb * 16);
      }
      #pragma unroll
      for (int mt = 0; mt < 4; ++mt)
        #pragma unroll
        for (int nt = 0; nt < 4; ++nt)
          acc[mt][nt] = __builtin_amdgcn_mfma_f32_16x16x32_f16(af[mt], bfv[nt], acc[mt][nt], 0, 0, 0);
    }
    __syncthreads();
  }

  if constexpr (OUT_MODE == 0) {
    _Float16* Cb = (_Float16*)Cp;
    #pragma unroll
    for (int mt = 0; mt < 4; ++mt)
      #pragma unroll
      for (int r = 0; r < 4; ++r) {
        size_t row = (size_t)(m0 + wm + mt * 16 + quad * 4 + r);
        #pragma unroll
        for (int nt = 0; nt < 4; ++nt)
          Cb[row * N + n0 + wn + nt * 16 + l15] = (_Float16)acc[mt][nt][r];
      }
  } else if constexpr (OUT_MODE == 2) {
    float* Cf = (float*)Cp;
    #pragma unroll
    for (int mt = 0; mt < 4; ++mt)
      #pragma unroll
      for (int r = 0; r < 4; ++r) {
        size_t row = (size_t)(m0 + wm + mt * 16 + quad * 4 + r);
        #pragma unroll
        for (int nt = 0; nt < 4; ++nt)
          Cf[row * N + n0 + wn + nt * 16 + l15] = acc[mt][nt][r];
      }
  } else if constexpr (OUT_MODE == 3) {
    const int half = N >> 1;
    if (n0 < half) {           // K-projection half: normal f16 store, ld = half
      _Float16* Cb = (_Float16*)Cp;
      #pragma unroll
      for (int mt = 0; mt < 4; ++mt)
        #pragma unroll
        for (int r = 0; r < 4; ++r) {
          size_t row = (size_t)(m0 + wm + mt * 16 + quad * 4 + r);
          #pragma unroll
          for (int nt = 0; nt < 4; ++nt)
            Cb[row * half + n0 + wn + nt * 16 + l15] = (_Float16)acc[mt][nt][r];
        }
    } else {                   // V-projection half: store transposed (feature-major)
      _Float16* Ct = (_Float16*)Cp2;
      #pragma unroll
      for (int mt = 0; mt < 4; ++mt)
        #pragma unroll
        for (int nt = 0; nt < 4; ++nt) {
          size_t crow = (size_t)(n0 - half + wn + nt * 16 + l15);
          size_t ccol = (size_t)(m0 + wm + mt * 16 + quad * 4);
          f16x4 t;
          t[0] = (_Float16)acc[mt][nt][0]; t[1] = (_Float16)acc[mt][nt][1];
          t[2] = (_Float16)acc[mt][nt][2]; t[3] = (_Float16)acc[mt][nt][3];
          *(f16x4*)(Ct + crow * M + ccol) = t;
        }
    }
  }
}

// ---------------- flash attention, non-causal, GQA 4:1 ----------------
// Q: (T, 4096) roped; Kg: (T, 1024) roped; Vt: (1024, T) transposed; O: (T, 4096)
// Double-buffered K/V staging (prefetch issued before compute, single barrier/iter),
// setprio around MFMA clusters, deferred-max online softmax in exp2 domain.
__global__ __launch_bounds__(256, 2)
void flash_kernel(const _Float16* __restrict__ Q, const _Float16* __restrict__ Kg,
                  const _Float16* __restrict__ Vt, _Float16* __restrict__ O,
                  int S, int T) {
  __shared__ __align__(16) _Float16 Kt[2][64 * 128];   // [buf][key][d], swizzled
  __shared__ __align__(16) _Float16 Vs[2][128 * 64];   // [buf][d][key], swizzled
  __shared__ __align__(16) _Float16 Ps[4 * 32 * 64];   // per-wave P [q][key], swizzled
  const int tid  = threadIdx.x;
  const int wave = tid >> 6, lane = tid & 63;
  const int l15  = lane & 15, quad = lane >> 4;
  const int qt = blockIdx.x, hq = blockIdx.y, b = blockIdx.z;
  const int kvh = hq >> 2;
  const float scale = 0.12751744f;   // log2(e)/sqrt(128): softmax in exp2 domain

  // Q fragments in registers: wave owns 32 q-rows
  f16x8 qf[2][4];
  #pragma unroll
  for (int mt = 0; mt < 2; ++mt)
    #pragma unroll
    for (int ks = 0; ks < 4; ++ks) {
      size_t row = (size_t)b * S + qt * 128 + wave * 32 + mt * 16 + l15;
      qf[mt][ks] = *(const f16x8*)(Q + row * 4096 + hq * 128 + ks * 32 + quad * 8);
    }

  f32x4 oacc[2][8] = {};
  float mi[2][4], li[2][4];
  #pragma unroll
  for (int mt = 0; mt < 2; ++mt)
    #pragma unroll
    for (int r = 0; r < 4; ++r) { mi[mt][r] = -1e30f; li[mt][r] = 0.f; }

  const int nkt = S >> 6;

  auto stage = [&](int kt, int buf) {
    #pragma unroll
    for (int i = 0; i < 4; ++i) {
      int base = wave * 256 + i * 64;
      int idx  = base + lane;
      { int row = idx >> 4, pos = idx & 15, c = pos ^ (row & 15);
        async16(Kg + (size_t)(b * S + kt * 64 + row) * 1024 + kvh * 128 + c * 8,
                (char*)Kt[buf] + base * 16); }
      { int row = idx >> 3, pos = idx & 7, c = pos ^ (row & 7);
        async16(Vt + (size_t)(kvh * 128 + row) * T + b * S + kt * 64 + c * 8,
                (char*)Vs[buf] + base * 16); }
    }
  };

  stage(0, 0);
  __syncthreads();           // drain prologue stage
  int cur = 0;

  for (int kt = 0; kt < nkt; ++kt) {
    // issue next tile's loads FIRST — latency hides under this iteration's compute
    if (kt + 1 < nkt) stage(kt + 1, cur ^ 1);

    // S = Q K^T   (32 q-rows x 64 keys per wave)
    f32x4 sacc[2][4] = {};
    #pragma unroll
    for (int ks = 0; ks < 4; ++ks) {
      f16x8 kf[4];
      #pragma unroll
      for (int nt = 0; nt < 4; ++nt) {
        int rk = nt * 16 + l15;
        int pp = (ks * 4 + quad) ^ (rk & 15);
        kf[nt] = *(const f16x8*)((const char*)Kt[cur] + rk * 256 + pp * 16);
      }
      __builtin_amdgcn_s_setprio(1);
      #pragma unroll
      for (int mt = 0; mt < 2; ++mt)
        #pragma unroll
        for (int nt = 0; nt < 4; ++nt)
          sacc[mt][nt] = __builtin_amdgcn_mfma_f32_16x16x32_f16(qf[mt][ks], kf[nt], sacc[mt][nt], 0, 0, 0);
      __builtin_amdgcn_s_setprio(0);
    }

    // online softmax (raw-domain max, deferred rescale, exp2 with fused scale)
    // C-layout: col=lane&15=key, row=quad*4+r=q
    #pragma unroll
    for (int mt = 0; mt < 2; ++mt) {
      float mx[4];
      #pragma unroll
      for (int r = 0; r < 4; ++r)
        mx[r] = fmaxf(fmaxf(sacc[mt][0][r], sacc[mt][1][r]),
                      fmaxf(sacc[mt][2][r], sacc[mt][3][r]));
      #pragma unroll
      for (int d = 1; d < 16; d <<= 1)
        #pragma unroll
        for (int r = 0; r < 4; ++r)
          mx[r] = fmaxf(mx[r], __shfl_xor(mx[r], d));
      // defer-max: only rescale when the running max actually grew (raw thresh 24 ≈ 3 in log2)
      bool grow = false;
      #pragma unroll
      for (int r = 0; r < 4; ++r) grow = grow || (mx[r] > mi[mt][r] + 24.0f);
      if (__any(grow)) {
        #pragma unroll
        for (int r = 0; r < 4; ++r) {
          float mnew = fmaxf(mi[mt][r], mx[r]);
          float al = exp2f((mi[mt][r] - mnew) * scale);
          mi[mt][r] = mnew;
          li[mt][r] *= al;
          #pragma unroll
          for (int nt = 0; nt < 8; ++nt) oacc[mt][nt][r] *= al;
        }
      }
      float nm[4], rs[4];
      #pragma unroll
      for (int r = 0; r < 4; ++r) { nm[r] = -mi[mt][r] * scale; rs[r] = 0.f; }
      #pragma unroll
      for (int nt = 0; nt < 4; ++nt)
        #pragma unroll
        for (int r = 0; r < 4; ++r) {
          float p = exp2f(fmaf(sacc[mt][nt][r], scale, nm[r]));
          sacc[mt][nt][r] = p;
          rs[r] += p;
        }
      #pragma unroll
      for (int d = 1; d < 16; d <<= 1)
        #pragma unroll
        for (int r = 0; r < 4; ++r)
          rs[r] += __shfl_xor(rs[r], d);
      #pragma unroll
      for (int r = 0; r < 4; ++r)
        li[mt][r] += rs[r];
      // P -> LDS (C-layout to A-operand layout round trip), swizzled
      #pragma unroll
      for (int nt = 0; nt < 4; ++nt)
        #pragma unroll
        for (int r = 0; r < 4; ++r) {
          int prow = mt * 16 + quad * 4 + r;
          int key  = nt * 16 + l15;
          int pos  = (key >> 3) ^ (prow & 7);
          Ps[wave * 2048 + prow * 64 + pos * 8 + (key & 7)] = (_Float16)sacc[mt][nt][r];
        }
    }

    // O += P V
    #pragma unroll
    for (int k2 = 0; k2 < 2; ++k2) {
      f16x8 pf[2], vf[8];
      #pragma unroll
      for (int mt = 0; mt < 2; ++mt) {
        int rp = mt * 16 + l15;
        int pp = (k2 * 4 + quad) ^ (rp & 7);
        pf[mt] = *(const f16x8*)((const char*)Ps + wave * 4096 + rp * 128 + pp * 16);
      }
      #pragma unroll
      for (int nt = 0; nt < 8; ++nt) {
        int rv = nt * 16 + l15;
        int pp = (k2 * 4 + quad) ^ (rv & 7);
        vf[nt] = *(const f16x8*)((const char*)Vs[cur] + rv * 128 + pp * 16);
      }
      __builtin_amdgcn_s_setprio(1);
      #pragma unroll
      for (int mt = 0; mt < 2; ++mt)
        #pragma unroll
        for (int nt = 0; nt < 8; ++nt)
          oacc[mt][nt] = __builtin_amdgcn_mfma_f32_16x16x32_f16(pf[mt], vf[nt], oacc[mt][nt], 0, 0, 0);
      __builtin_amdgcn_s_setprio(0);
    }

    // single barrier per iter: waits own prefetch (vmcnt) + all waves (barrier)
    __syncthreads();
    cur ^= 1;
  }

  // epilogue: O / l
  #pragma unroll
  for (int mt = 0; mt < 2; ++mt)
    #pragma unroll
    for (int r = 0; r < 4; ++r) {
      float inv = 1.0f / li[mt][r];
      size_t row = (size_t)b * S + qt * 128 + wave * 32 + mt * 16 + quad * 4 + r;
      #pragma unroll
      for (int nt = 0; nt < 8; ++nt)
        O[row * 4096 + hq * 128 + nt * 16 + l15] = (_Float16)(oacc[mt][nt][r] * inv);
    }
}

extern "C" void kernel_launch(void* const* d_in, const int* in_sizes, int n_in,
                              void* d_out, int out_size, void* d_ws, size_t ws_size,
                              hipStream_t stream) {
  const float* x  = (const float*)d_in[0];
  const float* wq = (const float*)d_in[1];
  const float* wk = (const float*)d_in[2];
  const float* wv = (const float*)d_in[3];
  const float* wo = (const float*)d_in[4];
  const int*   sp = (const int*)d_in[5];

  const int dim = 4096, kvdim = 1024;
  const int T = in_sizes[0] / dim;   // 4096 tokens (b*s)
  const int B = 2;
  const int S = T / B;               // 2048

  // workspace layout (fp16), total ~160 MiB
  _Float16* xb   = (_Float16*)d_ws;
  _Float16* wqb  = xb   + (size_t)T * dim;
  _Float16* wkvb = wqb  + (size_t)dim * dim;
  _Float16* wob  = wkvb + (size_t)2 * kvdim * dim;
  _Float16* XQ   = wob  + (size_t)dim * dim;
  _Float16* XK   = XQ   + (size_t)T * dim;
  _Float16* VT   = XK   + (size_t)T * kvdim;
  _Float16* AO   = xb;               // alias: xb dead after projections

  auto cvt = [&](const float* src, _Float16* dst, size_t n) {
    int n4 = (int)(n / 4);
    int blocks = (n4 + 255) / 256;
    if (blocks > 4096) blocks = 4096;
    cvt_kernel<<<blocks, 256, 0, stream>>>(src, dst, n4);
  };
  cvt(x,  xb,  (size_t)T * dim);
  cvt(wq, wqb, (size_t)dim * dim);
  cvt(wk, wkvb, (size_t)kvdim * dim);
  cvt(wv, wkvb + (size_t)kvdim * dim, (size_t)kvdim * dim);
  cvt(wo, wob, (size_t)dim * dim);

  // projections
  gemm_nt<0><<<dim3(dim / 128, T / 128), 256, 0, stream>>>(xb, wqb, XQ, nullptr, T, dim, dim);
  gemm_nt<3><<<dim3((2 * kvdim) / 128, T / 128), 256, 0, stream>>>(xb, wkvb, XK, VT, T, 2 * kvdim, dim);

  // RoPE (in place)
  rope_kernel<<<4096, 256, 0, stream>>>(XQ, sp, 11, S - 1, T * dim / 2);
  rope_kernel<<<2048, 256, 0, stream>>>(XK, sp,  9, S - 1, T * kvdim / 2);

  // attention
  flash_kernel<<<dim3(S / 128, 32, B), 256, 0, stream>>>(XQ, XK, VT, AO, S, T);

  // output projection (fp32 out)
  gemm_nt<2><<<dim3(dim / 128, T / 128), 256, 0, stream>>>(AO, wob, d_out, nullptr, T, dim, dim);
}